// Round 5
// baseline (38171.765 us; speedup 1.0000x reference)
//
#include <hip/hip_runtime.h>
#include <hip/hip_fp16.h>
#include <math.h>

namespace {
constexpr int Bn  = 512;
constexpr int Tn  = 100;
constexpr int Hn  = 256;
constexpr int En  = 256;
constexpr int D2n = 512;
constexpr int G4n = 1024;
constexpr float PENf = 1e6f;
constexpr size_t BIGN = (size_t)Bn * Tn * D2n;   // 26,214,400 elements
constexpr size_t SMALL_BYTES =
    ((size_t)2 * Bn * G4n + 5 * Bn * D2n + 3 * Bn * Tn + 4 * Bn * Hn + 4 * G4n) * 4;
}

using short8  = __attribute__((ext_vector_type(8))) short;
using floatx4 = __attribute__((ext_vector_type(4))) float;

// ---- type conversion helpers ----------------------------------------------
template<typename T> __device__ __forceinline__ float cvt_to_f(T x);
template<> __device__ __forceinline__ float cvt_to_f<float>(float x) { return x; }
template<> __device__ __forceinline__ float cvt_to_f<__half>(__half x) {
  return __half2float(x);
}
template<typename T> __device__ __forceinline__ T cvt_from_f(float x);
template<> __device__ __forceinline__ float cvt_from_f<float>(float x) { return x; }
template<> __device__ __forceinline__ __half cvt_from_f<__half>(float x) {
  return __float2half(x);
}
__device__ __forceinline__ float h2f_bits(unsigned short b) {
  __half_raw r; r.x = b; return __half2float(__half(r));
}
template<typename T> __device__ __forceinline__ float4 load4(const T* p);
template<> __device__ __forceinline__ float4 load4<float>(const float* p) {
  return *(const float4*)p;
}
template<> __device__ __forceinline__ float4 load4<__half>(const __half* p) {
  const ushort4 u = *(const ushort4*)p;
  float4 r;
  r.x = h2f_bits(u.x); r.y = h2f_bits(u.y);
  r.z = h2f_bits(u.z); r.w = h2f_bits(u.w);
  return r;
}
__device__ __forceinline__ float sigmoidf(float x) {
  return 1.0f / (1.0f + expf(-x));
}

// fp32 -> (hi bf16 truncate, lo bf16 rne of residual)
__device__ __forceinline__ void split2(float x, short& h, short& l) {
  const unsigned u  = __float_as_uint(x);
  const unsigned hu = u & 0xffff0000u;
  h = (short)(hu >> 16);
  const float r = x - __uint_as_float(hu);
  l = (short)((__float_as_uint(r) + 0x8000u) >> 16);
}
__device__ __forceinline__ void store4split(const float4 v, short* hp, short* lp) {
  short h0, h1, h2, h3, l0, l1, l2, l3;
  split2(v.x, h0, l0); split2(v.y, h1, l1);
  split2(v.z, h2, l2); split2(v.w, h3, l3);
  *(short4*)hp = make_short4(h0, h1, h2, h3);
  *(short4*)lp = make_short4(l0, l1, l2, l3);
}

// ---- manual grid barrier (all 256 blocks co-resident: 1 block/CU) ---------
__device__ __forceinline__ void grid_sync(unsigned* cnt, unsigned target) {
  __syncthreads();                // compiler drains vmcnt before s_barrier
  if (threadIdx.x == 0) {
    __threadfence();              // agent-scope release (L2 writeback)
    __hip_atomic_fetch_add(cnt, 1u, __ATOMIC_RELEASE, __HIP_MEMORY_SCOPE_AGENT);
    while (__hip_atomic_load(cnt, __ATOMIC_ACQUIRE, __HIP_MEMORY_SCOPE_AGENT) < target)
      __builtin_amdgcn_s_sleep(1);
    __threadfence();              // agent-scope acquire (invalidate)
  }
  __syncthreads();
}

// ---------------------------------------------------------------------------
// 64x64 tile GEMM: C (+)= A[64,K] * B[64,K]^T, split-bf16 MFMA (hh,hl,lh).
// Identical per-element summation order to the round-4 passing kernel.
// ---------------------------------------------------------------------------
template<typename CT, bool ACC>
__device__ __forceinline__ void gemm64(short* smem,
    const float* A, int lda, int m0,
    const float* B, int ldb, int n0, int K,
    CT* Cbase, size_t crstride, int tid) {
  short *Ahi = smem, *Alo = smem + 2048, *Bhi = smem + 4096, *Blo = smem + 6144;
  const int lane = tid & 63, wave = tid >> 6, qm = lane & 15, quad = lane >> 4;
  floatx4 acc[4];
#pragma unroll
  for (int nt = 0; nt < 4; ++nt) acc[nt] = (floatx4){0.f, 0.f, 0.f, 0.f};
  for (int k0 = 0; k0 < K; k0 += 32) {
    __syncthreads();
#pragma unroll
    for (int h2 = 0; h2 < 2; ++h2) {
      const int idx = tid + h2 * 256;
      const int r = idx >> 3, c4 = idx & 7;
      const int base = (c4 >> 1) * 512 + r * 8 + (c4 & 1) * 4;
      const float4 av = *(const float4*)(A + (size_t)(m0 + r) * lda + k0 + c4 * 4);
      store4split(av, &Ahi[base], &Alo[base]);
      const float4 bv = *(const float4*)(B + (size_t)(n0 + r) * ldb + k0 + c4 * 4);
      store4split(bv, &Bhi[base], &Blo[base]);
    }
    __syncthreads();
    const int abase = quad * 512 + (wave * 16 + qm) * 8;
    const short8 ah = *(const short8*)&Ahi[abase];
    const short8 al = *(const short8*)&Alo[abase];
#pragma unroll
    for (int nt = 0; nt < 4; ++nt) {
      const int bbase = quad * 512 + (nt * 16 + qm) * 8;
      const short8 bh = *(const short8*)&Bhi[bbase];
      const short8 bl = *(const short8*)&Blo[bbase];
      acc[nt] = __builtin_amdgcn_mfma_f32_16x16x32_bf16(ah, bh, acc[nt], 0, 0, 0);
      acc[nt] = __builtin_amdgcn_mfma_f32_16x16x32_bf16(ah, bl, acc[nt], 0, 0, 0);
      acc[nt] = __builtin_amdgcn_mfma_f32_16x16x32_bf16(al, bh, acc[nt], 0, 0, 0);
    }
  }
#pragma unroll
  for (int nt = 0; nt < 4; ++nt)
#pragma unroll
    for (int r2 = 0; r2 < 4; ++r2) {
      const int m = wave * 16 + quad * 4 + r2, n = nt * 16 + qm;
      CT* cp = Cbase + (size_t)m * crstride + n;
      float o = acc[nt][r2];
      if (ACC) o += cvt_to_f<CT>(*cp);
      *cp = cvt_from_f<CT>(o);
    }
}

// ---------------------------------------------------------------------------
// gate GEMM: 4 accs (i,f,g,o), out tile 64(m) x 16(h-slice) per gate.
// B rows remapped: row rr -> gate (rr>>4), h = hoff + (rr&15).
// ---------------------------------------------------------------------------
__device__ __forceinline__ void gates_gemm(floatx4 acc[4], short* smem,
    const float* A1, int lda1, const float* B1, int ldb1, int K1,
    const float* A2, int lda2, const float* B2, int ldb2, int K2,
    int m0, int hoff, int tid) {
  short *Ahi = smem, *Alo = smem + 2048, *Bhi = smem + 4096, *Blo = smem + 6144;
  const int lane = tid & 63, wave = tid >> 6, qm = lane & 15, quad = lane >> 4;
  for (int seg = 0; seg < 2; ++seg) {
    const float* A = seg ? A2 : A1;
    const float* B = seg ? B2 : B1;
    const int K = seg ? K2 : K1, lda = seg ? lda2 : lda1, ldb = seg ? ldb2 : ldb1;
    if (K <= 0 || A == nullptr) continue;
    for (int k0 = 0; k0 < K; k0 += 32) {
      __syncthreads();
#pragma unroll
      for (int h2 = 0; h2 < 2; ++h2) {
        const int idx = tid + h2 * 256;
        const int r = idx >> 3, c4 = idx & 7;
        const int base = (c4 >> 1) * 512 + r * 8 + (c4 & 1) * 4;
        const float4 av = *(const float4*)(A + (size_t)(m0 + r) * lda + k0 + c4 * 4);
        store4split(av, &Ahi[base], &Alo[base]);
        const int grow = (r >> 4) * Hn + hoff + (r & 15);
        const float4 bv = *(const float4*)(B + (size_t)grow * ldb + k0 + c4 * 4);
        store4split(bv, &Bhi[base], &Blo[base]);
      }
      __syncthreads();
      const int abase = quad * 512 + (wave * 16 + qm) * 8;
      const short8 ah = *(const short8*)&Ahi[abase];
      const short8 al = *(const short8*)&Alo[abase];
#pragma unroll
      for (int gg = 0; gg < 4; ++gg) {
        const int bbase = quad * 512 + (gg * 16 + qm) * 8;
        const short8 bh = *(const short8*)&Bhi[bbase];
        const short8 bl = *(const short8*)&Blo[bbase];
        acc[gg] = __builtin_amdgcn_mfma_f32_16x16x32_bf16(ah, bh, acc[gg], 0, 0, 0);
        acc[gg] = __builtin_amdgcn_mfma_f32_16x16x32_bf16(ah, bl, acc[gg], 0, 0, 0);
        acc[gg] = __builtin_amdgcn_mfma_f32_16x16x32_bf16(al, bh, acc[gg], 0, 0, 0);
      }
    }
  }
}

// ---------------------------------------------------------------------------
// Weff = Wih @ W_embed : [1024,2] per direction
__global__ void weff_kernel(const float* Wih_f, const float* Wih_b,
                            const float* W_embed, float* weff_f, float* weff_b) {
  const int gidx = blockIdx.x * 256 + threadIdx.x;
  if (gidx >= G4n) return;
  float f0 = 0.f, f1 = 0.f, b0 = 0.f, b1 = 0.f;
  for (int e = 0; e < En; ++e) {
    const float w0 = W_embed[e * 2 + 0];
    const float w1 = W_embed[e * 2 + 1];
    const float wf = Wih_f[gidx * En + e];
    const float wb = Wih_b[gidx * En + e];
    f0 = fmaf(wf, w0, f0); f1 = fmaf(wf, w1, f1);
    b0 = fmaf(wb, w0, b0); b1 = fmaf(wb, w1, b1);
  }
  weff_f[gidx * 2 + 0] = f0; weff_f[gidx * 2 + 1] = f1;
  weff_b[gidx * 2 + 0] = b0; weff_b[gidx * 2 + 1] = b1;
}

// ---------------------------------------------------------------------------
// Persistent encoder: 100 steps, 1 grid-sync/step. 256 blocks.
// gates job: dir(1) x btile(8) x hslice(16); ref job: ref(2) x dirsrc(2) x btile(8) x nslice(8)
// ---------------------------------------------------------------------------
template<typename ET, typename RT1, typename RT2>
struct EncP {
  const float* inputs;
  const float* Whh_f; const float* Whh_b;
  const float* b_f; const float* b_b;
  const float* weff_f; const float* weff_b;
  const float* W_ref; const float* W_ref2;
  float* hbuf;       // [2 parity][2 dir][512*256]
  float* c_dec;      // [2 dir][512*256]
  float* dec_out0;   // [512*512]
  ET* Enc; RT1* ref1; RT2* ref2;
  unsigned* barrier;
};

template<typename ET, typename RT1, typename RT2>
__global__ __launch_bounds__(256, 1) void enc_coop(EncP<ET, RT1, RT2> P) {
  __shared__ __align__(16) short smem[8192];
  const int bid = blockIdx.x, tid = threadIdx.x;
  const int dir = bid >> 7, btile = (bid >> 4) & 7, hs = bid & 15;
  const int r_ref = (bid >> 7) & 1, r_dir = (bid >> 6) & 1;
  const int r_bt = (bid >> 3) & 7, r_ns = bid & 7;
  const int lane = tid & 63, wave = tid >> 6, qm = lane & 15, quad = lane >> 4;
  const int hcol = hs * 16 + qm;
  const float* Whh  = dir ? P.Whh_b : P.Whh_f;
  const float* bias = dir ? P.b_b : P.b_f;
  const float* weff = dir ? P.weff_b : P.weff_f;
  float c_reg[4] = {0.f, 0.f, 0.f, 0.f};
  float h_reg[4] = {0.f, 0.f, 0.f, 0.f};
  unsigned sync_no = 0;

  auto ref_job = [&](const float* hpar, int pos) {
    const float* hsrc = hpar + (size_t)r_dir * (Bn * Hn);
    if (r_ref == 0)
      gemm64<RT1, true>(smem, hsrc, Hn, r_bt * 64,
                        P.W_ref + r_dir * Hn, D2n, r_ns * 64, Hn,
                        P.ref1 + (size_t)(r_bt * 64) * Tn * D2n + (size_t)pos * D2n + r_ns * 64,
                        (size_t)Tn * D2n, tid);
    else
      gemm64<RT2, true>(smem, hsrc, Hn, r_bt * 64,
                        P.W_ref2 + r_dir * Hn, D2n, r_ns * 64, Hn,
                        P.ref2 + (size_t)(r_bt * 64) * Tn * D2n + (size_t)pos * D2n + r_ns * 64,
                        (size_t)Tn * D2n, tid);
  };

  for (int t = 0; t < Tn; ++t) {
    const float* hprev = P.hbuf + (size_t)((t - 1) & 1) * (2 * Bn * Hn);
    // ref accumulation from h(t-1)
    if (t > 0) ref_job(hprev, r_dir ? (Tn - t) : (t - 1));
    // gates
    floatx4 acc[4];
#pragma unroll
    for (int gg = 0; gg < 4; ++gg) acc[gg] = (floatx4){0.f, 0.f, 0.f, 0.f};
    if (t > 0)
      gates_gemm(acc, smem, hprev + (size_t)dir * (Bn * Hn), Hn, Whh, Hn, Hn,
                 nullptr, 0, nullptr, 0, 0, btile * 64, hs * 16, tid);
    // epilogue: bias + rank-2 x term, then LSTM
    const int tcur = dir ? (Tn - 1 - t) : t;
    float xa[4], xb2[4];
#pragma unroll
    for (int r2 = 0; r2 < 4; ++r2) {
      const int m = btile * 64 + wave * 16 + quad * 4 + r2;
      xa[r2]  = P.inputs[(size_t)m * (Tn * 2) + tcur * 2 + 0];
      xb2[r2] = P.inputs[(size_t)m * (Tn * 2) + tcur * 2 + 1];
    }
    float gv[4][4];
#pragma unroll
    for (int gg = 0; gg < 4; ++gg) {
      const int grow = gg * Hn + hcol;
      const float bn = bias[grow];
      const float w20 = weff[grow * 2], w21 = weff[grow * 2 + 1];
#pragma unroll
      for (int r2 = 0; r2 < 4; ++r2) {
        float o = acc[gg][r2] + bn;
        o = fmaf(xa[r2], w20, fmaf(xb2[r2], w21, o));
        gv[gg][r2] = o;
      }
    }
    float* hdst = P.hbuf + (size_t)(t & 1) * (2 * Bn * Hn) + (size_t)dir * (Bn * Hn);
    const int tt = dir ? (Tn - 1 - t) : t;
#pragma unroll
    for (int r2 = 0; r2 < 4; ++r2) {
      const float cn = sigmoidf(gv[1][r2]) * c_reg[r2] +
                       sigmoidf(gv[0][r2]) * tanhf(gv[2][r2]);
      c_reg[r2] = cn;
      const float hn = sigmoidf(gv[3][r2]) * tanhf(cn);
      h_reg[r2] = hn;
      const int m = btile * 64 + wave * 16 + quad * 4 + r2;
      hdst[(size_t)m * Hn + hcol] = hn;
      P.Enc[(size_t)m * Tn * D2n + (size_t)tt * D2n + dir * Hn + hcol] = cvt_from_f<ET>(hn);
    }
    grid_sync(P.barrier, 256u * (++sync_no));
  }
  // final ref contributions from h(99) (parity (Tn-1)&1 == 1)
  ref_job(P.hbuf + (size_t)1 * (2 * Bn * Hn), r_dir ? 0 : (Tn - 1));
  // finals for decoder (from registers)
#pragma unroll
  for (int r2 = 0; r2 < 4; ++r2) {
    const int m = btile * 64 + wave * 16 + quad * 4 + r2;
    P.dec_out0[(size_t)m * D2n + dir * Hn + hcol] = h_reg[r2];
    P.c_dec[((size_t)dir * Bn + m) * Hn + hcol] = c_reg[r2];
  }
}

// ---------------------------------------------------------------------------
// Persistent decoder: 100 steps, 3 grid-syncs/step. 256 blocks.
// ---------------------------------------------------------------------------
template<typename ET, typename RT1, typename RT2>
struct DecP {
  const int* test_roads;
  const float* Wih_f; const float* Whh_f; const float* b_f;
  const float* Wih_b; const float* Whh_b; const float* b_b;
  const float* W_q; const float* W_q2; const float* v; const float* v2;
  const ET* Enc; const RT1* ref1; const RT2* ref2;
  float* dec_out;    // [2][512*512]
  float* xb;         // [2][512*512]
  float* qb; float* q2b;
  const float* c_init;  // [2][512*256]
  float* loss;       // d_out [512]
  unsigned* barrier;
};

template<typename ET, typename RT1, typename RT2>
__global__ __launch_bounds__(256, 1) void dec_coop(DecP<ET, RT1, RT2> P) {
  __shared__ __align__(16) short smem[8192];
  __shared__ float s1l[2][104], s2l[2][104];
  __shared__ float awl[104];
  __shared__ float redf[256];
  __shared__ int   redi[256];
  __shared__ float playedl[2][104];
  __shared__ float lossl[2];
  const int bid = blockIdx.x, tid = threadIdx.x;
  const int dir = bid >> 7, btile = (bid >> 4) & 7, hs = bid & 15;
  const int lane = tid & 63, wave = tid >> 6, qm = lane & 15, quad = lane >> 4;
  const int hcol = hs * 16 + qm;
  const float* Wih  = dir ? P.Wih_b : P.Wih_f;
  const float* Whh  = dir ? P.Whh_b : P.Whh_f;
  const float* bias = dir ? P.b_b : P.b_f;
  float c_reg[4];
#pragma unroll
  for (int r2 = 0; r2 < 4; ++r2) {
    const int m = btile * 64 + wave * 16 + quad * 4 + r2;
    c_reg[r2] = P.c_init[((size_t)dir * Bn + m) * Hn + hcol];
  }
  if (tid < Tn) { playedl[0][tid] = 0.f; playedl[1][tid] = 0.f; }
  if (tid < 2) lossl[tid] = 0.f;
  // P2 job mapping (first 128 blocks)
  const int proj = bid >> 6, pbt = (bid >> 3) & 7, pn = bid & 7;
  // P3 mapping: wave -> (local b, attn)
  const int ab = wave >> 1, attn = wave & 1;
  const int gb = bid * 2 + ab;
  unsigned sync_no = 0;
  __syncthreads();

  for (int t = 0; t < Tn; ++t) {
    const float* xc  = P.xb + (size_t)(t & 1) * (Bn * D2n);
    const float* dcur = P.dec_out + (size_t)(t & 1) * (Bn * D2n);
    float* dnext = P.dec_out + (size_t)((t + 1) & 1) * (Bn * D2n);
    // ---- P1: cell gates + LSTM ----
    floatx4 acc[4];
#pragma unroll
    for (int gg = 0; gg < 4; ++gg) acc[gg] = (floatx4){0.f, 0.f, 0.f, 0.f};
    gates_gemm(acc, smem, xc, D2n, Wih, D2n, D2n,
               dcur + dir * Hn, D2n, Whh, Hn, Hn, btile * 64, hs * 16, tid);
#pragma unroll
    for (int gg = 0; gg < 4; ++gg) {
      const float bn = bias[gg * Hn + hcol];
#pragma unroll
      for (int r2 = 0; r2 < 4; ++r2) acc[gg][r2] += bn;
    }
#pragma unroll
    for (int r2 = 0; r2 < 4; ++r2) {
      const float cn = sigmoidf(acc[1][r2]) * c_reg[r2] +
                       sigmoidf(acc[0][r2]) * tanhf(acc[2][r2]);
      c_reg[r2] = cn;
      const float hn = sigmoidf(acc[3][r2]) * tanhf(cn);
      const int m = btile * 64 + wave * 16 + quad * 4 + r2;
      dnext[(size_t)m * D2n + dir * Hn + hcol] = hn;
    }
    grid_sync(P.barrier, 256u * (++sync_no));
    // ---- P2: q projections (128 jobs) ----
    if (bid < 128) {
      const float* A = proj ? xc : dnext;
      const float* B = proj ? P.W_q2 : P.W_q;
      float* C = (proj ? P.q2b : P.qb) + (size_t)(pbt * 64) * D2n + pn * 64;
      gemm64<float, false>(smem, A, D2n, pbt * 64, B, D2n, pn * 64, D2n,
                           C, D2n, tid);
    }
    grid_sync(P.barrier, 256u * (++sync_no));
    // ---- P3: attention for this block's 2 b's, into LDS ----
    {
      const float* qrow = (attn ? P.q2b : P.qb) + (size_t)gb * D2n;
      const float* vp = attn ? P.v2 : P.v;
      const int e0 = lane * 4, e1 = (64 + lane) * 4;
      const float4 q0 = *(const float4*)&qrow[e0];
      const float4 q1 = *(const float4*)&qrow[e1];
      const float4 v0 = *(const float4*)&vp[e0];
      const float4 v1 = *(const float4*)&vp[e1];
      float* sdst = attn ? &s2l[ab][0] : &s1l[ab][0];
#pragma unroll 2
      for (int j = 0; j < Tn; ++j) {
        float4 r0, r1;
        if (attn == 0) {
          const RT1* row = P.ref1 + ((size_t)gb * Tn + j) * D2n;
          r0 = load4<RT1>(row + e0); r1 = load4<RT1>(row + e1);
        } else {
          const RT2* row = P.ref2 + ((size_t)gb * Tn + j) * D2n;
          r0 = load4<RT2>(row + e0); r1 = load4<RT2>(row + e1);
        }
        float a = 0.f;
        a = fmaf(tanhf(r0.x + q0.x), v0.x, a);
        a = fmaf(tanhf(r0.y + q0.y), v0.y, a);
        a = fmaf(tanhf(r0.z + q0.z), v0.z, a);
        a = fmaf(tanhf(r0.w + q0.w), v0.w, a);
        a = fmaf(tanhf(r1.x + q1.x), v1.x, a);
        a = fmaf(tanhf(r1.y + q1.y), v1.y, a);
        a = fmaf(tanhf(r1.z + q1.z), v1.z, a);
        a = fmaf(tanhf(r1.w + q1.w), v1.w, a);
#pragma unroll
        for (int off = 32; off > 0; off >>= 1) a += __shfl_xor(a, off, 64);
        if (lane == 0) sdst[j] = a;
      }
    }
    __syncthreads();
    // ---- P4: softmax/argmax/lse/x_new for owned b's ----
    float* xnextbuf = P.xb + (size_t)((t + 1) & 1) * (Bn * D2n);
    for (int lb = 0; lb < 2; ++lb) {
      const int b = bid * 2 + lb;
      const float uval = (tid < Tn) ? s2l[lb][tid] : -INFINITY;
      const float owval = (tid < Tn) ? (s1l[lb][tid] - PENf * playedl[lb][tid])
                                     : -INFINITY;
      redf[tid] = uval; __syncthreads();
      for (int s = 128; s > 0; s >>= 1) {
        if (tid < s) redf[tid] = fmaxf(redf[tid], redf[tid + s]);
        __syncthreads();
      }
      const float umax = redf[0]; __syncthreads();
      const float e = (tid < Tn) ? expf(uval - umax) : 0.f;
      redf[tid] = e; __syncthreads();
      for (int s = 128; s > 0; s >>= 1) {
        if (tid < s) redf[tid] += redf[tid + s];
        __syncthreads();
      }
      const float usum = redf[0]; __syncthreads();
      if (tid < Tn) awl[tid] = e / usum;
      // argmax (first-index tie-break)
      redf[tid] = owval; redi[tid] = (tid < Tn) ? tid : 0x7fffffff; __syncthreads();
      for (int s = 128; s > 0; s >>= 1) {
        if (tid < s) {
          const float ov = redf[tid + s]; const int oi = redi[tid + s];
          if (ov > redf[tid] || (ov == redf[tid] && oi < redi[tid])) {
            redf[tid] = ov; redi[tid] = oi;
          }
        }
        __syncthreads();
      }
      const float omax = redf[0]; const int sel = redi[0]; __syncthreads();
      const float eo = (tid < Tn) ? expf(owval - omax) : 0.f;
      redf[tid] = eo; __syncthreads();
      for (int s = 128; s > 0; s >>= 1) {
        if (tid < s) redf[tid] += redf[tid + s];
        __syncthreads();
      }
      if (tid == 0) {
        const float lse = omax + logf(redf[0]);
        const int tgt = P.test_roads[b * Tn + t];
        const float owt = s1l[lb][tgt] - PENf * playedl[lb][tgt];
        lossl[lb] += lse - owt;
        playedl[lb][sel] += 1.f;
      }
      __syncthreads();
      // x_new
      const ET* Eb = P.Enc + (size_t)b * Tn * D2n;
      float* xn = xnextbuf + (size_t)b * D2n;
      for (int k = tid; k < D2n; k += 256) {
        float a2 = 0.f;
#pragma unroll 4
        for (int j = 0; j < Tn; ++j)
          a2 = fmaf(awl[j], cvt_to_f<ET>(Eb[(size_t)j * D2n + k]), a2);
        xn[k] = a2;
      }
      __syncthreads();
    }
    grid_sync(P.barrier, 256u * (++sync_no));
  }
  if (tid == 0) {
    P.loss[bid * 2]     = lossl[0];
    P.loss[bid * 2 + 1] = lossl[1];
  }
}

// ---------------------------------------------------------------------------
template<typename ET, typename RT1, typename RT2>
static void run_all(void* const* d_in, void* d_out, char* ws, hipStream_t stream) {
  const float* inputs     = (const float*)d_in[0];
  const int*   test_roads = (const int*)d_in[1];
  const float* W_embed    = (const float*)d_in[2];
  const float* enc_Wih_f  = (const float*)d_in[3];
  const float* enc_Whh_f  = (const float*)d_in[4];
  const float* enc_b_f    = (const float*)d_in[5];
  const float* enc_Wih_b  = (const float*)d_in[6];
  const float* enc_Whh_b  = (const float*)d_in[7];
  const float* enc_b_b    = (const float*)d_in[8];
  const float* dec_Wih_f  = (const float*)d_in[9];
  const float* dec_Whh_f  = (const float*)d_in[10];
  const float* dec_b_f    = (const float*)d_in[11];
  const float* dec_Wih_b  = (const float*)d_in[12];
  const float* dec_Whh_b  = (const float*)d_in[13];
  const float* dec_b_b    = (const float*)d_in[14];
  const float* W_ref      = (const float*)d_in[15];
  const float* W_q        = (const float*)d_in[16];
  const float* v          = (const float*)d_in[17];
  const float* W_ref2     = (const float*)d_in[18];
  const float* W_q2       = (const float*)d_in[19];
  const float* v2         = (const float*)d_in[20];

  char* p0 = ws;
  ET*  Enc  = (ET*)p0;  p0 += BIGN * sizeof(ET);
  RT1* ref1 = (RT1*)p0; p0 += BIGN * sizeof(RT1);
  RT2* ref2 = (RT2*)p0; p0 += BIGN * sizeof(RT2);
  unsigned* barrier = (unsigned*)p0;                   // 256 B reserved
  float* xb      = (float*)(p0 + 256);                 // 2 * 512*512
  float* dec_out = xb + 2 * Bn * D2n;                  // 2 * 512*512
  float* hbuf    = dec_out + 2 * Bn * D2n;             // 2 * 2 * 512*256
  float* c_dec   = hbuf + 4 * Bn * Hn;                 // 2 * 512*256
  float* qb      = c_dec + 2 * Bn * Hn;
  float* q2b     = qb + Bn * D2n;
  float* weff_f  = q2b + Bn * D2n;
  float* weff_b  = weff_f + G4n * 2;

  // zero: refs (accumulated), barrier counters + xb0
  hipMemsetAsync(ref1, 0, BIGN * (sizeof(RT1) + sizeof(RT2)), stream);
  hipMemsetAsync(barrier, 0, 256 + (size_t)Bn * D2n * 4, stream);

  weff_kernel<<<G4n / 256, 256, 0, stream>>>(enc_Wih_f, enc_Wih_b, W_embed,
                                             weff_f, weff_b);

  EncP<ET, RT1, RT2> ep = { inputs, enc_Whh_f, enc_Whh_b, enc_b_f, enc_b_b,
                            weff_f, weff_b, W_ref, W_ref2,
                            hbuf, c_dec, dec_out, Enc, ref1, ref2, barrier };
  enc_coop<ET, RT1, RT2><<<256, 256, 0, stream>>>(ep);

  DecP<ET, RT1, RT2> dp = { test_roads,
                            dec_Wih_f, dec_Whh_f, dec_b_f,
                            dec_Wih_b, dec_Whh_b, dec_b_b,
                            W_q, W_q2, v, v2,
                            Enc, ref1, ref2,
                            dec_out, xb, qb, q2b, c_dec,
                            (float*)d_out, barrier + 1 };
  dec_coop<ET, RT1, RT2><<<256, 256, 0, stream>>>(dp);
}

// ---------------------------------------------------------------------------
extern "C" void kernel_launch(void* const* d_in, const int* in_sizes, int n_in,
                              void* d_out, int out_size, void* d_ws, size_t ws_size,
                              hipStream_t stream) {
  (void)in_sizes; (void)n_in; (void)out_size;
  char* ws = (char*)d_ws;
  const size_t szA = 3 * BIGN * 4 + SMALL_BYTES;               // all f32
  const size_t szB = 2 * BIGN * 4 + BIGN * 2 + SMALL_BYTES;    // Enc f16
  const size_t szC = BIGN * 4 + 2 * BIGN * 2 + SMALL_BYTES;    // + ref2 f16
  if (ws_size >= szA)      run_all<float,  float,  float >(d_in, d_out, ws, stream);
  else if (ws_size >= szB) run_all<__half, float,  float >(d_in, d_out, ws, stream);
  else if (ws_size >= szC) run_all<__half, float,  __half>(d_in, d_out, ws, stream);
  else                     run_all<__half, __half, __half>(d_in, d_out, ws, stream);
}

// Round 6
// 23501.736 us; speedup vs baseline: 1.6242x; 1.6242x over previous
//
#include <hip/hip_runtime.h>
#include <hip/hip_fp16.h>
#include <math.h>

namespace {
constexpr int Bn  = 512;
constexpr int Tn  = 100;
constexpr int Hn  = 256;
constexpr int En  = 256;
constexpr int D2n = 512;
constexpr int G4n = 1024;
constexpr float PENf = 1e6f;
constexpr size_t BIGN = (size_t)Bn * Tn * D2n;   // 26,214,400 elements
constexpr size_t SMALL_BYTES =
    ((size_t)2 * Bn * G4n + 5 * Bn * D2n + 3 * Bn * Tn + 4 * Bn * Hn + 4 * G4n) * 4;
}

using short8  = __attribute__((ext_vector_type(8))) short;
using floatx4 = __attribute__((ext_vector_type(4))) float;

// ---- type conversion helpers ----------------------------------------------
template<typename T> __device__ __forceinline__ float cvt_to_f(T x);
template<> __device__ __forceinline__ float cvt_to_f<float>(float x) { return x; }
template<> __device__ __forceinline__ float cvt_to_f<__half>(__half x) {
  return __half2float(x);
}
template<typename T> __device__ __forceinline__ T cvt_from_f(float x);
template<> __device__ __forceinline__ float cvt_from_f<float>(float x) { return x; }
template<> __device__ __forceinline__ __half cvt_from_f<__half>(float x) {
  return __float2half(x);
}
__device__ __forceinline__ float h2f_bits(unsigned short b) {
  __half_raw r; r.x = b; return __half2float(__half(r));
}
template<typename T> __device__ __forceinline__ float4 load4(const T* p);
template<> __device__ __forceinline__ float4 load4<float>(const float* p) {
  return *(const float4*)p;
}
template<> __device__ __forceinline__ float4 load4<__half>(const __half* p) {
  const ushort4 u = *(const ushort4*)p;
  float4 r;
  r.x = h2f_bits(u.x); r.y = h2f_bits(u.y);
  r.z = h2f_bits(u.z); r.w = h2f_bits(u.w);
  return r;
}
__device__ __forceinline__ float sigmoidf(float x) {
  return 1.0f / (1.0f + expf(-x));
}
__device__ __forceinline__ float fast_tanhf(float x) {
  // monotone, saturates correctly, ~1e-7 rel err
  return 1.0f - 2.0f / (__expf(2.0f * x) + 1.0f);
}

// fp32 -> (hi bf16 truncate, lo bf16 rne of residual)
__device__ __forceinline__ void split2(float x, short& h, short& l) {
  const unsigned u  = __float_as_uint(x);
  const unsigned hu = u & 0xffff0000u;
  h = (short)(hu >> 16);
  const float r = x - __uint_as_float(hu);
  l = (short)((__float_as_uint(r) + 0x8000u) >> 16);
}
__device__ __forceinline__ void store4split(const float4 v, short* hp, short* lp) {
  short h0, h1, h2, h3, l0, l1, l2, l3;
  split2(v.x, h0, l0); split2(v.y, h1, l1);
  split2(v.z, h2, l2); split2(v.w, h3, l3);
  *(short4*)hp = make_short4(h0, h1, h2, h3);
  *(short4*)lp = make_short4(l0, l1, l2, l3);
}

// ---- manual grid barrier (256 blocks, 1/CU co-resident) -------------------
// Release fence (wbl2) ONCE, relaxed inc, relaxed RMW-poll (no cache
// maintenance per poll!), acquire fence (inv) ONCE after exit.
__device__ __forceinline__ void grid_sync(unsigned* cnt, unsigned target) {
  __syncthreads();
  if (threadIdx.x == 0) {
    __builtin_amdgcn_fence(__ATOMIC_RELEASE, "agent");
    __hip_atomic_fetch_add(cnt, 1u, __ATOMIC_RELAXED, __HIP_MEMORY_SCOPE_AGENT);
    while (__hip_atomic_fetch_add(cnt, 0u, __ATOMIC_RELAXED,
                                  __HIP_MEMORY_SCOPE_AGENT) < target)
      __builtin_amdgcn_s_sleep(1);
    __builtin_amdgcn_fence(__ATOMIC_ACQUIRE, "agent");
  }
  __syncthreads();
}

// ---------------------------------------------------------------------------
// 64x64 tile GEMM: C (+)= A[64,K] * B[64,K]^T, split-bf16 MFMA (hh,hl,lh).
// ---------------------------------------------------------------------------
template<typename CT, bool ACC>
__device__ __forceinline__ void gemm64(short* smem,
    const float* A, int lda, int m0,
    const float* B, int ldb, int n0, int K,
    CT* Cbase, size_t crstride, int tid) {
  short *Ahi = smem, *Alo = smem + 2048, *Bhi = smem + 4096, *Blo = smem + 6144;
  const int lane = tid & 63, wave = tid >> 6, qm = lane & 15, quad = lane >> 4;
  floatx4 acc[4];
#pragma unroll
  for (int nt = 0; nt < 4; ++nt) acc[nt] = (floatx4){0.f, 0.f, 0.f, 0.f};
  for (int k0 = 0; k0 < K; k0 += 32) {
    __syncthreads();
#pragma unroll
    for (int h2 = 0; h2 < 2; ++h2) {
      const int idx = tid + h2 * 256;
      const int r = idx >> 3, c4 = idx & 7;
      const int base = (c4 >> 1) * 512 + r * 8 + (c4 & 1) * 4;
      const float4 av = *(const float4*)(A + (size_t)(m0 + r) * lda + k0 + c4 * 4);
      store4split(av, &Ahi[base], &Alo[base]);
      const float4 bv = *(const float4*)(B + (size_t)(n0 + r) * ldb + k0 + c4 * 4);
      store4split(bv, &Bhi[base], &Blo[base]);
    }
    __syncthreads();
    const int abase = quad * 512 + (wave * 16 + qm) * 8;
    const short8 ah = *(const short8*)&Ahi[abase];
    const short8 al = *(const short8*)&Alo[abase];
#pragma unroll
    for (int nt = 0; nt < 4; ++nt) {
      const int bbase = quad * 512 + (nt * 16 + qm) * 8;
      const short8 bh = *(const short8*)&Bhi[bbase];
      const short8 bl = *(const short8*)&Blo[bbase];
      acc[nt] = __builtin_amdgcn_mfma_f32_16x16x32_bf16(ah, bh, acc[nt], 0, 0, 0);
      acc[nt] = __builtin_amdgcn_mfma_f32_16x16x32_bf16(ah, bl, acc[nt], 0, 0, 0);
      acc[nt] = __builtin_amdgcn_mfma_f32_16x16x32_bf16(al, bh, acc[nt], 0, 0, 0);
    }
  }
#pragma unroll
  for (int nt = 0; nt < 4; ++nt)
#pragma unroll
    for (int r2 = 0; r2 < 4; ++r2) {
      const int m = wave * 16 + quad * 4 + r2, n = nt * 16 + qm;
      CT* cp = Cbase + (size_t)m * crstride + n;
      float o = acc[nt][r2];
      if (ACC) o += cvt_to_f<CT>(*cp);
      *cp = cvt_from_f<CT>(o);
    }
}

// ---------------------------------------------------------------------------
// gate GEMM: 4 accs (i,f,g,o), out tile 64(m) x 16(h-slice) per gate.
// ---------------------------------------------------------------------------
__device__ __forceinline__ void gates_gemm(floatx4 acc[4], short* smem,
    const float* A1, int lda1, const float* B1, int ldb1, int K1,
    const float* A2, int lda2, const float* B2, int ldb2, int K2,
    int m0, int hoff, int tid) {
  short *Ahi = smem, *Alo = smem + 2048, *Bhi = smem + 4096, *Blo = smem + 6144;
  const int lane = tid & 63, wave = tid >> 6, qm = lane & 15, quad = lane >> 4;
  for (int seg = 0; seg < 2; ++seg) {
    const float* A = seg ? A2 : A1;
    const float* B = seg ? B2 : B1;
    const int K = seg ? K2 : K1, lda = seg ? lda2 : lda1, ldb = seg ? ldb2 : ldb1;
    if (K <= 0 || A == nullptr) continue;
    for (int k0 = 0; k0 < K; k0 += 32) {
      __syncthreads();
#pragma unroll
      for (int h2 = 0; h2 < 2; ++h2) {
        const int idx = tid + h2 * 256;
        const int r = idx >> 3, c4 = idx & 7;
        const int base = (c4 >> 1) * 512 + r * 8 + (c4 & 1) * 4;
        const float4 av = *(const float4*)(A + (size_t)(m0 + r) * lda + k0 + c4 * 4);
        store4split(av, &Ahi[base], &Alo[base]);
        const int grow = (r >> 4) * Hn + hoff + (r & 15);
        const float4 bv = *(const float4*)(B + (size_t)grow * ldb + k0 + c4 * 4);
        store4split(bv, &Bhi[base], &Blo[base]);
      }
      __syncthreads();
      const int abase = quad * 512 + (wave * 16 + qm) * 8;
      const short8 ah = *(const short8*)&Ahi[abase];
      const short8 al = *(const short8*)&Alo[abase];
#pragma unroll
      for (int gg = 0; gg < 4; ++gg) {
        const int bbase = quad * 512 + (gg * 16 + qm) * 8;
        const short8 bh = *(const short8*)&Bhi[bbase];
        const short8 bl = *(const short8*)&Blo[bbase];
        acc[gg] = __builtin_amdgcn_mfma_f32_16x16x32_bf16(ah, bh, acc[gg], 0, 0, 0);
        acc[gg] = __builtin_amdgcn_mfma_f32_16x16x32_bf16(ah, bl, acc[gg], 0, 0, 0);
        acc[gg] = __builtin_amdgcn_mfma_f32_16x16x32_bf16(al, bh, acc[gg], 0, 0, 0);
      }
    }
  }
}

// ---------------------------------------------------------------------------
__global__ void weff_kernel(const float* Wih_f, const float* Wih_b,
                            const float* W_embed, float* weff_f, float* weff_b) {
  const int gidx = blockIdx.x * 256 + threadIdx.x;
  if (gidx >= G4n) return;
  float f0 = 0.f, f1 = 0.f, b0 = 0.f, b1 = 0.f;
  for (int e = 0; e < En; ++e) {
    const float w0 = W_embed[e * 2 + 0];
    const float w1 = W_embed[e * 2 + 1];
    const float wf = Wih_f[gidx * En + e];
    const float wb = Wih_b[gidx * En + e];
    f0 = fmaf(wf, w0, f0); f1 = fmaf(wf, w1, f1);
    b0 = fmaf(wb, w0, b0); b1 = fmaf(wb, w1, b1);
  }
  weff_f[gidx * 2 + 0] = f0; weff_f[gidx * 2 + 1] = f1;
  weff_b[gidx * 2 + 0] = b0; weff_b[gidx * 2 + 1] = b1;
}

// ---------------------------------------------------------------------------
// Persistent encoder: 100 steps, 1 grid-sync/step. 256 blocks.
// ---------------------------------------------------------------------------
template<typename ET, typename RT1, typename RT2>
struct EncP {
  const float* inputs;
  const float* Whh_f; const float* Whh_b;
  const float* b_f; const float* b_b;
  const float* weff_f; const float* weff_b;
  const float* W_ref; const float* W_ref2;
  float* hbuf;       // [2 parity][2 dir][512*256]
  float* c_dec;      // [2 dir][512*256]
  float* dec_out0;   // [512*512]
  ET* Enc; RT1* ref1; RT2* ref2;
  unsigned* barrier;
};

template<typename ET, typename RT1, typename RT2>
__global__ __launch_bounds__(256, 1) void enc_coop(EncP<ET, RT1, RT2> P) {
  __shared__ __align__(16) short smem[8192];
  const int bid = blockIdx.x, tid = threadIdx.x;
  const int dir = bid >> 7, btile = (bid >> 4) & 7, hs = bid & 15;
  const int r_ref = (bid >> 7) & 1, r_dir = (bid >> 6) & 1;
  const int r_bt = (bid >> 3) & 7, r_ns = bid & 7;
  const int lane = tid & 63, wave = tid >> 6, qm = lane & 15, quad = lane >> 4;
  const int hcol = hs * 16 + qm;
  const float* Whh  = dir ? P.Whh_b : P.Whh_f;
  const float* bias = dir ? P.b_b : P.b_f;
  const float* weff = dir ? P.weff_b : P.weff_f;
  float c_reg[4] = {0.f, 0.f, 0.f, 0.f};
  float h_reg[4] = {0.f, 0.f, 0.f, 0.f};
  unsigned sync_no = 0;

  auto ref_job = [&](const float* hpar, int pos) {
    const float* hsrc = hpar + (size_t)r_dir * (Bn * Hn);
    if (r_ref == 0)
      gemm64<RT1, true>(smem, hsrc, Hn, r_bt * 64,
                        P.W_ref + r_dir * Hn, D2n, r_ns * 64, Hn,
                        P.ref1 + (size_t)(r_bt * 64) * Tn * D2n + (size_t)pos * D2n + r_ns * 64,
                        (size_t)Tn * D2n, tid);
    else
      gemm64<RT2, true>(smem, hsrc, Hn, r_bt * 64,
                        P.W_ref2 + r_dir * Hn, D2n, r_ns * 64, Hn,
                        P.ref2 + (size_t)(r_bt * 64) * Tn * D2n + (size_t)pos * D2n + r_ns * 64,
                        (size_t)Tn * D2n, tid);
  };

  for (int t = 0; t < Tn; ++t) {
    const float* hprev = P.hbuf + (size_t)((t - 1) & 1) * (2 * Bn * Hn);
    if (t > 0) ref_job(hprev, r_dir ? (Tn - t) : (t - 1));
    floatx4 acc[4];
#pragma unroll
    for (int gg = 0; gg < 4; ++gg) acc[gg] = (floatx4){0.f, 0.f, 0.f, 0.f};
    if (t > 0)
      gates_gemm(acc, smem, hprev + (size_t)dir * (Bn * Hn), Hn, Whh, Hn, Hn,
                 nullptr, 0, nullptr, 0, 0, btile * 64, hs * 16, tid);
    const int tcur = dir ? (Tn - 1 - t) : t;
    float xa[4], xb2[4];
#pragma unroll
    for (int r2 = 0; r2 < 4; ++r2) {
      const int m = btile * 64 + wave * 16 + quad * 4 + r2;
      xa[r2]  = P.inputs[(size_t)m * (Tn * 2) + tcur * 2 + 0];
      xb2[r2] = P.inputs[(size_t)m * (Tn * 2) + tcur * 2 + 1];
    }
    float gv[4][4];
#pragma unroll
    for (int gg = 0; gg < 4; ++gg) {
      const int grow = gg * Hn + hcol;
      const float bn = bias[grow];
      const float w20 = weff[grow * 2], w21 = weff[grow * 2 + 1];
#pragma unroll
      for (int r2 = 0; r2 < 4; ++r2) {
        float o = acc[gg][r2] + bn;
        o = fmaf(xa[r2], w20, fmaf(xb2[r2], w21, o));
        gv[gg][r2] = o;
      }
    }
    float* hdst = P.hbuf + (size_t)(t & 1) * (2 * Bn * Hn) + (size_t)dir * (Bn * Hn);
    const int tt = dir ? (Tn - 1 - t) : t;
#pragma unroll
    for (int r2 = 0; r2 < 4; ++r2) {
      const float cn = sigmoidf(gv[1][r2]) * c_reg[r2] +
                       sigmoidf(gv[0][r2]) * tanhf(gv[2][r2]);
      c_reg[r2] = cn;
      const float hn = sigmoidf(gv[3][r2]) * tanhf(cn);
      h_reg[r2] = hn;
      const int m = btile * 64 + wave * 16 + quad * 4 + r2;
      hdst[(size_t)m * Hn + hcol] = hn;
      P.Enc[(size_t)m * Tn * D2n + (size_t)tt * D2n + dir * Hn + hcol] = cvt_from_f<ET>(hn);
    }
    grid_sync(P.barrier, 256u * (++sync_no));
  }
  ref_job(P.hbuf + (size_t)1 * (2 * Bn * Hn), r_dir ? 0 : (Tn - 1));
#pragma unroll
  for (int r2 = 0; r2 < 4; ++r2) {
    const int m = btile * 64 + wave * 16 + quad * 4 + r2;
    P.dec_out0[(size_t)m * D2n + dir * Hn + hcol] = h_reg[r2];
    P.c_dec[((size_t)dir * Bn + m) * Hn + hcol] = c_reg[r2];
  }
}

// ---------------------------------------------------------------------------
// Persistent decoder: 100 steps, 3 grid-syncs/step. 256 blocks.
// ---------------------------------------------------------------------------
template<typename ET, typename RT1, typename RT2>
struct DecP {
  const int* test_roads;
  const float* Wih_f; const float* Whh_f; const float* b_f;
  const float* Wih_b; const float* Whh_b; const float* b_b;
  const float* W_q; const float* W_q2; const float* v; const float* v2;
  const ET* Enc; const RT1* ref1; const RT2* ref2;
  float* dec_out;    // [2][512*512]
  float* xb;         // [2][512*512]
  float* qb; float* q2b;
  const float* c_init;  // [2][512*256]
  float* loss;       // d_out [512]
  unsigned* barrier;
};

template<typename ET, typename RT1, typename RT2>
__global__ __launch_bounds__(256, 1) void dec_coop(DecP<ET, RT1, RT2> P) {
  __shared__ __align__(16) short smem[8192];
  __shared__ float s1l[2][104], s2l[2][104];
  __shared__ float awl[2][104];
  __shared__ float redf[2][128];
  __shared__ int   redi[2][128];
  __shared__ float playedl[2][104];
  __shared__ float lossl[2];
  const int bid = blockIdx.x, tid = threadIdx.x;
  const int dir = bid >> 7, btile = (bid >> 4) & 7, hs = bid & 15;
  const int lane = tid & 63, wave = tid >> 6, qm = lane & 15, quad = lane >> 4;
  const int hcol = hs * 16 + qm;
  const float* Wih  = dir ? P.Wih_b : P.Wih_f;
  const float* Whh  = dir ? P.Whh_b : P.Whh_f;
  const float* bias = dir ? P.b_b : P.b_f;
  float c_reg[4];
#pragma unroll
  for (int r2 = 0; r2 < 4; ++r2) {
    const int m = btile * 64 + wave * 16 + quad * 4 + r2;
    c_reg[r2] = P.c_init[((size_t)dir * Bn + m) * Hn + hcol];
  }
  if (tid < Tn) { playedl[0][tid] = 0.f; playedl[1][tid] = 0.f; }
  if (tid < 2) lossl[tid] = 0.f;
  const int proj = bid >> 6, pbt = (bid >> 3) & 7, pn = bid & 7;
  const int ab = wave >> 1, attn = wave & 1;
  const int gb = bid * 2 + ab;
  const int half = tid >> 7, htid = tid & 127;
  unsigned sync_no = 0;
  __syncthreads();

  for (int t = 0; t < Tn; ++t) {
    const float* xc  = P.xb + (size_t)(t & 1) * (Bn * D2n);
    const float* dcur = P.dec_out + (size_t)(t & 1) * (Bn * D2n);
    float* dnext = P.dec_out + (size_t)((t + 1) & 1) * (Bn * D2n);
    // ---- P1: cell gates + LSTM ----
    floatx4 acc[4];
#pragma unroll
    for (int gg = 0; gg < 4; ++gg) acc[gg] = (floatx4){0.f, 0.f, 0.f, 0.f};
    gates_gemm(acc, smem, xc, D2n, Wih, D2n, D2n,
               dcur + dir * Hn, D2n, Whh, Hn, Hn, btile * 64, hs * 16, tid);
#pragma unroll
    for (int gg = 0; gg < 4; ++gg) {
      const float bn = bias[gg * Hn + hcol];
#pragma unroll
      for (int r2 = 0; r2 < 4; ++r2) acc[gg][r2] += bn;
    }
#pragma unroll
    for (int r2 = 0; r2 < 4; ++r2) {
      const float cn = sigmoidf(acc[1][r2]) * c_reg[r2] +
                       sigmoidf(acc[0][r2]) * tanhf(acc[2][r2]);
      c_reg[r2] = cn;
      const float hn = sigmoidf(acc[3][r2]) * tanhf(cn);
      const int m = btile * 64 + wave * 16 + quad * 4 + r2;
      dnext[(size_t)m * D2n + dir * Hn + hcol] = hn;
    }
    grid_sync(P.barrier, 256u * (++sync_no));
    // ---- P2: q projections (128 jobs) ----
    if (bid < 128) {
      const float* A = proj ? xc : dnext;
      const float* B = proj ? P.W_q2 : P.W_q;
      float* C = (proj ? P.q2b : P.qb) + (size_t)(pbt * 64) * D2n + pn * 64;
      gemm64<float, false>(smem, A, D2n, pbt * 64, B, D2n, pn * 64, D2n,
                           C, D2n, tid);
    }
    grid_sync(P.barrier, 256u * (++sync_no));
    // ---- P3: attention for this block's 2 b's, into LDS ----
    {
      const float* qrow = (attn ? P.q2b : P.qb) + (size_t)gb * D2n;
      const float* vp = attn ? P.v2 : P.v;
      const int e0 = lane * 4, e1 = (64 + lane) * 4;
      const float4 q0 = *(const float4*)&qrow[e0];
      const float4 q1 = *(const float4*)&qrow[e1];
      const float4 v0 = *(const float4*)&vp[e0];
      const float4 v1 = *(const float4*)&vp[e1];
      float* sdst = attn ? &s2l[ab][0] : &s1l[ab][0];
#pragma unroll 2
      for (int j = 0; j < Tn; ++j) {
        float4 r0, r1;
        if (attn == 0) {
          const RT1* row = P.ref1 + ((size_t)gb * Tn + j) * D2n;
          r0 = load4<RT1>(row + e0); r1 = load4<RT1>(row + e1);
        } else {
          const RT2* row = P.ref2 + ((size_t)gb * Tn + j) * D2n;
          r0 = load4<RT2>(row + e0); r1 = load4<RT2>(row + e1);
        }
        float a = 0.f;
        a = fmaf(fast_tanhf(r0.x + q0.x), v0.x, a);
        a = fmaf(fast_tanhf(r0.y + q0.y), v0.y, a);
        a = fmaf(fast_tanhf(r0.z + q0.z), v0.z, a);
        a = fmaf(fast_tanhf(r0.w + q0.w), v0.w, a);
        a = fmaf(fast_tanhf(r1.x + q1.x), v1.x, a);
        a = fmaf(fast_tanhf(r1.y + q1.y), v1.y, a);
        a = fmaf(fast_tanhf(r1.z + q1.z), v1.z, a);
        a = fmaf(fast_tanhf(r1.w + q1.w), v1.w, a);
#pragma unroll
        for (int off = 32; off > 0; off >>= 1) a += __shfl_xor(a, off, 64);
        if (lane == 0) sdst[j] = a;
      }
    }
    __syncthreads();
    // ---- P4: both owned b's in parallel on half-blocks ----
    {
      float* xnextbuf = P.xb + (size_t)((t + 1) & 1) * (Bn * D2n);
      const int b = bid * 2 + half;
      float* rf = &redf[half][0];
      int*   ri = &redi[half][0];
      const float uval = (htid < Tn) ? s2l[half][htid] : -INFINITY;
      const float owval = (htid < Tn) ? (s1l[half][htid] - PENf * playedl[half][htid])
                                      : -INFINITY;
      rf[htid] = uval; __syncthreads();
      for (int s = 64; s > 0; s >>= 1) {
        if (htid < s) rf[htid] = fmaxf(rf[htid], rf[htid + s]);
        __syncthreads();
      }
      const float umax = rf[0]; __syncthreads();
      const float e = (htid < Tn) ? __expf(uval - umax) : 0.f;
      rf[htid] = e; __syncthreads();
      for (int s = 64; s > 0; s >>= 1) {
        if (htid < s) rf[htid] += rf[htid + s];
        __syncthreads();
      }
      const float usum = rf[0]; __syncthreads();
      if (htid < Tn) awl[half][htid] = e / usum;
      // argmax (first-index tie-break)
      rf[htid] = owval; ri[htid] = (htid < Tn) ? htid : 0x7fffffff; __syncthreads();
      for (int s = 64; s > 0; s >>= 1) {
        if (htid < s) {
          const float ov = rf[htid + s]; const int oi = ri[htid + s];
          if (ov > rf[htid] || (ov == rf[htid] && oi < ri[htid])) {
            rf[htid] = ov; ri[htid] = oi;
          }
        }
        __syncthreads();
      }
      const float omax = rf[0]; const int sel = ri[0]; __syncthreads();
      const float eo = (htid < Tn) ? __expf(owval - omax) : 0.f;
      rf[htid] = eo; __syncthreads();
      for (int s = 64; s > 0; s >>= 1) {
        if (htid < s) rf[htid] += rf[htid + s];
        __syncthreads();
      }
      if (htid == 0) {
        const float lse = omax + __logf(rf[0]);
        const int tgt = P.test_roads[b * Tn + t];
        const float owt = s1l[half][tgt] - PENf * playedl[half][tgt];
        lossl[half] += lse - owt;
        playedl[half][sel] += 1.f;
      }
      __syncthreads();
      // x_new
      const ET* Eb = P.Enc + (size_t)b * Tn * D2n;
      float* xn = xnextbuf + (size_t)b * D2n;
      for (int k = htid; k < D2n; k += 128) {
        float a2 = 0.f;
#pragma unroll 4
        for (int j = 0; j < Tn; ++j)
          a2 = fmaf(awl[half][j], cvt_to_f<ET>(Eb[(size_t)j * D2n + k]), a2);
        xn[k] = a2;
      }
    }
    grid_sync(P.barrier, 256u * (++sync_no));
  }
  if (tid == 0) {
    P.loss[bid * 2]     = lossl[0];
    P.loss[bid * 2 + 1] = lossl[1];
  }
}

// ---------------------------------------------------------------------------
template<typename ET, typename RT1, typename RT2>
static void run_all(void* const* d_in, void* d_out, char* ws, hipStream_t stream) {
  const float* inputs     = (const float*)d_in[0];
  const int*   test_roads = (const int*)d_in[1];
  const float* W_embed    = (const float*)d_in[2];
  const float* enc_Wih_f  = (const float*)d_in[3];
  const float* enc_Whh_f  = (const float*)d_in[4];
  const float* enc_b_f    = (const float*)d_in[5];
  const float* enc_Wih_b  = (const float*)d_in[6];
  const float* enc_Whh_b  = (const float*)d_in[7];
  const float* enc_b_b    = (const float*)d_in[8];
  const float* dec_Wih_f  = (const float*)d_in[9];
  const float* dec_Whh_f  = (const float*)d_in[10];
  const float* dec_b_f    = (const float*)d_in[11];
  const float* dec_Wih_b  = (const float*)d_in[12];
  const float* dec_Whh_b  = (const float*)d_in[13];
  const float* dec_b_b    = (const float*)d_in[14];
  const float* W_ref      = (const float*)d_in[15];
  const float* W_q        = (const float*)d_in[16];
  const float* v          = (const float*)d_in[17];
  const float* W_ref2     = (const float*)d_in[18];
  const float* W_q2       = (const float*)d_in[19];
  const float* v2         = (const float*)d_in[20];

  char* p0 = ws;
  ET*  Enc  = (ET*)p0;  p0 += BIGN * sizeof(ET);
  RT1* ref1 = (RT1*)p0; p0 += BIGN * sizeof(RT1);
  RT2* ref2 = (RT2*)p0; p0 += BIGN * sizeof(RT2);
  unsigned* barrier = (unsigned*)p0;                   // 256 B reserved
  float* xb      = (float*)(p0 + 256);                 // 2 * 512*512
  float* dec_out = xb + 2 * Bn * D2n;                  // 2 * 512*512
  float* hbuf    = dec_out + 2 * Bn * D2n;             // 2 * 2 * 512*256
  float* c_dec   = hbuf + 4 * Bn * Hn;                 // 2 * 512*256
  float* qb      = c_dec + 2 * Bn * Hn;
  float* q2b     = qb + Bn * D2n;
  float* weff_f  = q2b + Bn * D2n;
  float* weff_b  = weff_f + G4n * 2;

  hipMemsetAsync(ref1, 0, BIGN * (sizeof(RT1) + sizeof(RT2)), stream);
  hipMemsetAsync(barrier, 0, 256 + (size_t)Bn * D2n * 4, stream);

  weff_kernel<<<G4n / 256, 256, 0, stream>>>(enc_Wih_f, enc_Wih_b, W_embed,
                                             weff_f, weff_b);

  EncP<ET, RT1, RT2> ep = { inputs, enc_Whh_f, enc_Whh_b, enc_b_f, enc_b_b,
                            weff_f, weff_b, W_ref, W_ref2,
                            hbuf, c_dec, dec_out, Enc, ref1, ref2, barrier };
  enc_coop<ET, RT1, RT2><<<256, 256, 0, stream>>>(ep);

  DecP<ET, RT1, RT2> dp = { test_roads,
                            dec_Wih_f, dec_Whh_f, dec_b_f,
                            dec_Wih_b, dec_Whh_b, dec_b_b,
                            W_q, W_q2, v, v2,
                            Enc, ref1, ref2,
                            dec_out, xb, qb, q2b, c_dec,
                            (float*)d_out, barrier + 1 };
  dec_coop<ET, RT1, RT2><<<256, 256, 0, stream>>>(dp);
}

// ---------------------------------------------------------------------------
extern "C" void kernel_launch(void* const* d_in, const int* in_sizes, int n_in,
                              void* d_out, int out_size, void* d_ws, size_t ws_size,
                              hipStream_t stream) {
  (void)in_sizes; (void)n_in; (void)out_size;
  char* ws = (char*)d_ws;
  const size_t szA = 3 * BIGN * 4 + SMALL_BYTES;               // all f32
  const size_t szB = 2 * BIGN * 4 + BIGN * 2 + SMALL_BYTES;    // Enc f16
  const size_t szC = BIGN * 4 + 2 * BIGN * 2 + SMALL_BYTES;    // + ref2 f16
  if (ws_size >= szA)      run_all<float,  float,  float >(d_in, d_out, ws, stream);
  else if (ws_size >= szB) run_all<__half, float,  float >(d_in, d_out, ws, stream);
  else if (ws_size >= szC) run_all<__half, float,  __half>(d_in, d_out, ws, stream);
  else                     run_all<__half, __half, __half>(d_in, d_out, ws, stream);
}